// Round 18
// baseline (184.446 us; speedup 1.0000x reference)
//
#include <hip/hip_runtime.h>
#include <math.h>

typedef unsigned short u16;
typedef __attribute__((ext_vector_type(8))) short short8;
typedef __attribute__((ext_vector_type(4))) float float4v;
typedef __attribute__((ext_vector_type(4))) u16 ushort4v;

namespace {
constexpr int kT    = 2048;
constexpr int kDim  = 1024;
constexpr int kH    = 16;
constexpr int kHKV  = 4;
constexpr int kD    = 64;
constexpr int kTok  = 4096;   // B*T
}

__device__ __forceinline__ u16 f2bf(float f) {
  unsigned int u = __builtin_bit_cast(unsigned int, f);
  u = (u + 0x7FFFu + ((u >> 16) & 1u)) >> 16;   // RNE
  return (u16)u;
}

// packed f32x2 -> bf16x2 (RNE, bitwise-identical to f2bf); lo = src0.
__device__ __forceinline__ unsigned int cvtpk(float lo, float hi) {
  unsigned int r;
  asm("v_cvt_pk_bf16_f32 %0, %1, %2" : "=v"(r) : "v"(lo), "v"(hi));
  return r;
}

// ---------------- fused prep: rope table + x->bf16 + 4x fake-quant -----------
// blocks [0,128): rope table; [128,2176): cvt x; [2176,4736): quant rows.
__global__ __launch_bounds__(256) void prep_kernel(
    const float* __restrict__ x,
    const float* __restrict__ w_q, const float* __restrict__ w_k,
    const float* __restrict__ w_v, const float* __restrict__ w_proj,
    u16* __restrict__ xb, u16* __restrict__ wqkv, u16* __restrict__ wpq,
    float2* __restrict__ ropetab)
{
  __shared__ float red[4];
  const int bid = blockIdx.x, tid = threadIdx.x;

  if (bid < 128) {                       // rope table (bitwise-same transcendentals)
    const int idx = bid * 256 + tid;     // 0..32767
    const int t = idx >> 4, i = idx & 15;
    const float fr = (float)t * powf(10000.0f, -(float)i * (1.0f / 16.0f));
    ropetab[idx] = make_float2(cosf(fr), sinf(fr));
    return;
  }
  if (bid < 2176) {                      // x -> bf16, 8 elems/thread
    const size_t i = ((size_t)(bid - 128) * 256 + tid) * 8;
    const float4 a = *(const float4*)(x + i);
    const float4 b = *(const float4*)(x + i + 4);
    uint4 o;
    o.x = cvtpk(a.x, a.y); o.y = cvtpk(a.z, a.w);
    o.z = cvtpk(b.x, b.y); o.w = cvtpk(b.z, b.w);
    *(uint4*)(xb + i) = o;
    return;
  }
  // fake-quant: one block per weight row (1024 cols, 4/thread, register-held)
  const int rid = bid - 2176;            // 0..2559
  const float* src; u16* dst; float halfv;
  if (rid < 1024)      { src = w_q    + (size_t)rid * 1024;          dst = wqkv + (size_t)rid * 1024;          halfv = 32.0f; }
  else if (rid < 1280) { src = w_k    + (size_t)(rid - 1024) * 1024; dst = wqkv + (size_t)rid * 1024;          halfv = 32.0f; }
  else if (rid < 1536) { src = w_v    + (size_t)(rid - 1280) * 1024; dst = wqkv + (size_t)rid * 1024;          halfv = 16.0f; }
  else                 { src = w_proj + (size_t)(rid - 1536) * 1024; dst = wpq  + (size_t)(rid - 1536) * 1024; halfv = 16.0f; }

  const float4 v4 = *(const float4*)(src + tid * 4);
  float mx = fmaxf(fmaxf(fabsf(v4.x), fabsf(v4.y)), fmaxf(fabsf(v4.z), fabsf(v4.w)));
  #pragma unroll
  for (int m = 1; m < 64; m <<= 1) mx = fmaxf(mx, __shfl_xor(mx, m));
  if ((tid & 63) == 0) red[tid >> 6] = mx;
  __syncthreads();
  mx = fmaxf(fmaxf(red[0], red[1]), fmaxf(red[2], red[3]));
  const float wmax = fmaxf(mx, 1e-5f);
  const float inv_half = 1.0f / halfv;
  const float vals[4] = {v4.x, v4.y, v4.z, v4.w};
  float q[4];
  #pragma unroll
  for (int j = 0; j < 4; ++j) {
    float r = rintf(vals[j] / wmax * halfv);
    r = fminf(fmaxf(r, -halfv), halfv - 1.0f);
    q[j] = r * inv_half * wmax;
  }
  uint2 o;
  o.x = cvtpk(q[0], q[1]); o.y = cvtpk(q[2], q[3]);
  *(uint2*)(dst + tid * 4) = o;
}

// ======== 128Mx64N bf16 MFMA GEMM core (4 waves x 32x64, BK=32) ==============
// Reg-staged global->LDS with XOR swizzle (measured-best structure, R0).
// Each wave: rows wm..wm+31 (mi in {0,1}), all 64 cols (ni 0..3).
// acc[mi][ni][i]: row = by*128 + wv*32 + mi*16 + quad*4 + i, col = ni*16 + n.
#define GEMM_CORE(A_, W_, K_, NCOL0_)                                          \
  __shared__ u16 As[128][32];                                                  \
  __shared__ u16 Bs[64][32];                                                   \
  const int tid = threadIdx.x;                                                 \
  const int lane = tid & 63, wv = tid >> 6;                                    \
  const int n = lane & 15, quad = lane >> 4;                                   \
  const int wm = wv * 32;                                                      \
  const int m0 = blockIdx.y * 128;                                             \
  const int sr = tid >> 2, sc = (tid & 3) * 8;                                 \
  const int scs = sc ^ ((sr & 3) * 8);                                         \
  float4v acc[2][4];                                                           \
  _Pragma("unroll")                                                            \
  for (int mi = 0; mi < 2; ++mi)                                               \
    _Pragma("unroll")                                                          \
    for (int ni = 0; ni < 4; ++ni) {                                           \
      acc[mi][ni][0]=0.f; acc[mi][ni][1]=0.f;                                  \
      acc[mi][ni][2]=0.f; acc[mi][ni][3]=0.f; }                                \
  short8 a0r, a1r, b0r;                                                        \
  a0r = *(const short8*)(A_ + (size_t)(m0 + sr) * K_ + sc);                    \
  a1r = *(const short8*)(A_ + (size_t)(m0 + sr + 64) * K_ + sc);               \
  b0r = *(const short8*)(W_ + (size_t)(NCOL0_ + sr) * K_ + sc);                \
  for (int k0 = 0; k0 < K_; k0 += 32) {                                        \
    __syncthreads();                                                           \
    *(short8*)&As[sr][scs] = a0r;  *(short8*)&As[sr + 64][scs] = a1r;          \
    *(short8*)&Bs[sr][scs] = b0r;                                              \
    __syncthreads();                                                           \
    if (k0 + 32 < K_) {                                                        \
      a0r = *(const short8*)(A_ + (size_t)(m0 + sr) * K_ + k0 + 32 + sc);      \
      a1r = *(const short8*)(A_ + (size_t)(m0 + sr + 64) * K_ + k0 + 32 + sc); \
      b0r = *(const short8*)(W_ + (size_t)(NCOL0_ + sr) * K_ + k0 + 32 + sc);  \
    }                                                                          \
    short8 af[2], bf[4];                                                       \
    _Pragma("unroll")                                                          \
    for (int mi = 0; mi < 2; ++mi)                                             \
      af[mi] = *(const short8*)&As[wm + mi * 16 + n][(quad * 8) ^ ((n & 3) * 8)]; \
    _Pragma("unroll")                                                          \
    for (int ni = 0; ni < 4; ++ni)                                             \
      bf[ni] = *(const short8*)&Bs[ni * 16 + n][(quad * 8) ^ ((n & 3) * 8)];   \
    _Pragma("unroll")                                                          \
    for (int mi = 0; mi < 2; ++mi)                                             \
      _Pragma("unroll")                                                        \
      for (int ni = 0; ni < 4; ++ni)                                           \
        acc[mi][ni] = __builtin_amdgcn_mfma_f32_16x16x32_bf16(af[mi], bf[ni], acc[mi][ni], 0, 0, 0); \
  }

// -------- QKV GEMM with fused RMSNorm+RoPE+gain epilogue ---------------------
// Panel (blockIdx.x, 64 cols): 0..15 q head, 16..19 k head, 20..23 v head.
__global__ __launch_bounds__(256) void gemm_qkv(
    const u16* __restrict__ A, const u16* __restrict__ W,
    const float2* __restrict__ ropetab, const float* __restrict__ q_gain,
    u16* __restrict__ qh, u16* __restrict__ kh,
    u16* __restrict__ vT, float* __restrict__ vcmp)
{
  GEMM_CORE(A, W, kDim, (int)(blockIdx.x * 64))

  const int p = blockIdx.x;
  const int rbase = m0 + wm;                 // + mi*16 + quad*4 + i = token row
  const int bI = rbase >> 11;                // batch (128-row tiles never straddle)

  if (p < 20) {
    // q (head h=p) or k (head p-16): RMSNorm over 64 dims + RoPE + gain
    const float gain = (p < 16) ? q_gain[p] * 0.125f : 1.0f;
    u16* dst = (p < 16) ? qh + ((size_t)(bI * kH + p) * kT) * kD
                        : kh + ((size_t)(bI * kHKV + (p - 16)) * kT) * kD;
    #pragma unroll
    for (int mi = 0; mi < 2; ++mi)
      #pragma unroll
      for (int i = 0; i < 4; ++i) {
        const int row = rbase + mi * 16 + quad * 4 + i;
        const int t = row & (kT - 1);
        float v[4];
        #pragma unroll
        for (int ni = 0; ni < 4; ++ni) v[ni] = acc[mi][ni][i];
        float ss = v[0]*v[0] + v[1]*v[1] + v[2]*v[2] + v[3]*v[3];
        #pragma unroll
        for (int m = 1; m < 16; m <<= 1) ss += __shfl_xor(ss, m);
        const float rr = 1.0f / sqrtf(ss * (1.0f / 64.0f) + 1.1920929e-7f);
        #pragma unroll
        for (int ni = 0; ni < 4; ++ni) v[ni] *= rr;
        const float2 cs = ropetab[t * 16 + n];
        const float r0 =  v[0] * cs.x + v[1] * cs.y;
        const float r1 = -v[0] * cs.y + v[1] * cs.x;
        v[0] = r0; v[1] = r1;
        #pragma unroll
        for (int ni = 0; ni < 4; ++ni)
          dst[(size_t)t * kD + ni * 16 + n] = f2bf(v[ni] * gain);
      }
  } else {
    // v head kvh = p-20: bf16 V^T [b][kv][d][T] + compact fp32 v [tok][kv*64+d]
    const int kvh = p - 20;
    u16* vTb = vT + ((size_t)(bI * kHKV + kvh) * kD) * kT;
    #pragma unroll
    for (int mi = 0; mi < 2; ++mi) {
      const int t0 = (rbase + mi * 16 + quad * 4) & (kT - 1);
      #pragma unroll
      for (int ni = 0; ni < 4; ++ni) {
        const int d = ni * 16 + n;
        uint2 pk;
        pk.x = cvtpk(acc[mi][ni][0], acc[mi][ni][1]);
        pk.y = cvtpk(acc[mi][ni][2], acc[mi][ni][3]);
        *(uint2*)(vTb + (size_t)d * kT + t0) = pk;
        #pragma unroll
        for (int i = 0; i < 4; ++i)
          vcmp[(size_t)(rbase + mi * 16 + quad * 4 + i) * (kHKV * kD) + kvh * kD + d] = acc[mi][ni][i];
      }
    }
  }
}

// -------- output projection GEMM (fp32 C) ------------------------------------
__global__ __launch_bounds__(256) void gemm_out(
    const u16* __restrict__ A, const u16* __restrict__ W,
    float* __restrict__ C)
{
  GEMM_CORE(A, W, kDim, (int)(blockIdx.x * 64))
  const int n0 = blockIdx.x * 64;
  #pragma unroll
  for (int mi = 0; mi < 2; ++mi)
    #pragma unroll
    for (int ni = 0; ni < 4; ++ni)
      #pragma unroll
      for (int i = 0; i < 4; ++i)
        C[(size_t)(m0 + wm + mi * 16 + quad * 4 + i) * kDim + n0 + ni * 16 + n] = acc[mi][ni][i];
}

// ---------------- MFMA causal flash attention, S^T orientation ---------------
// ADJACENT-paired tiles per block: block bx owns tiles {30-2bx, 31-2bx}.
// Both chains live for every iteration except the last (~95% dual-chain ILP,
// vs ~52% for the old (p, 31-p) pairing). Longest block (bx=0) launches first.
// S^T = mfma(K_frag, Q_frag): one softmax row per lane (quad-replicated).
// PV as O^T = mfma(V^T_frag, P_frag). Static max 12 (|q'|<=1.5, |k|=8).
__global__ __launch_bounds__(256) void attn_mfma(
    const u16* __restrict__ qh, const u16* __restrict__ kh,
    const u16* __restrict__ vT, const float* __restrict__ vcmp,
    u16* __restrict__ yo)
{
  __shared__ u16 ks[64][64];     // [key][d],   col ^= (key&7)*8
  __shared__ u16 vs[64][64];     // [d][key],   col ^= (d&7)*8   (V^T)
  __shared__ u16 ps[4][16][64];  // [wave][query][key], col ^= (query&7)*8

  const int tid = threadIdx.x;
  const int lane = tid & 63, wq = tid >> 6;
  const int n = lane & 15, quad = lane >> 4;
  const int p = blockIdx.x;                     // 0..15, longest first
  const int h = blockIdx.y, b = blockIdx.z;
  const int kv = h >> 2;
  const int tiles[2] = {30 - 2 * p, 31 - 2 * p};  // adjacent pair (short, long)
  const u16* kbase = kh + ((size_t)(b * kHKV + kv) * kT) * kD;
  const u16* vbase = vT + ((size_t)(b * kHKV + kv) * kD) * kT;

  short8 qa[2][2];                // Q B-frags (col=query n, k=d contiguous)
  {
    const u16* qb = qh + ((size_t)(b * kH + h) * kT) * kD;
    #pragma unroll
    for (int u = 0; u < 2; ++u) {
      const size_t row = (size_t)(tiles[u] * 64 + wq * 16 + n) * kD;
      qa[u][0] = *(const short8*)(qb + row + quad * 8);
      qa[u][1] = *(const short8*)(qb + row + 32 + quad * 8);
    }
  }

  const int sr = tid >> 3;            // 0..31 (+32 second chunk)
  const int sc = (tid & 7) * 8;
  const int scs = sc ^ ((sr & 7) * 8);

  float l_r[2] = {0.0f, 0.0f};
  float4v acc[2][4];                  // O^T: [u][d-block g][i]: d=g*16+quad*4+i, query=n
  #pragma unroll
  for (int u = 0; u < 2; ++u)
    #pragma unroll
    for (int g = 0; g < 4; ++g) { acc[u][g][0]=0.f; acc[u][g][1]=0.f; acc[u][g][2]=0.f; acc[u][g][3]=0.f; }

  short8 kr0, kr1, vr0, vr1;
  auto loadKV = [&](int kt) {
    kr0 = *(const short8*)(kbase + (size_t)(kt * 64 + sr) * kD + sc);
    kr1 = *(const short8*)(kbase + (size_t)(kt * 64 + sr + 32) * kD + sc);
    vr0 = *(const short8*)(vbase + (size_t)sr * kT + kt * 64 + sc);
    vr1 = *(const short8*)(vbase + (size_t)(sr + 32) * kT + kt * 64 + sc);
  };

  auto process = [&](int u, int kt) {
    float4v s[4];
    #pragma unroll
    for (int g = 0; g < 4; ++g) { s[g][0]=0.f; s[g][1]=0.f; s[g][2]=0.f; s[g][3]=0.f; }
    // S^T[key][query]: A = K rows, B = Q
    #pragma unroll
    for (int g = 0; g < 4; ++g) {
      const short8 kb0 = *(const short8*)&ks[g * 16 + n][(quad * 8) ^ ((n & 7) * 8)];
      s[g] = __builtin_amdgcn_mfma_f32_16x16x32_bf16(kb0, qa[u][0], s[g], 0, 0, 0);
      const short8 kb1 = *(const short8*)&ks[g * 16 + n][(32 + quad * 8) ^ ((n & 7) * 8)];
      s[g] = __builtin_amdgcn_mfma_f32_16x16x32_bf16(kb1, qa[u][1], s[g], 0, 0, 0);
    }
    if (kt == tiles[u]) {   // diagonal: mask key j > query m (local coords)
      const int mloc = wq * 16 + n;
      #pragma unroll
      for (int g = 0; g < 4; ++g)
        #pragma unroll
        for (int i = 0; i < 4; ++i)
          if (g * 16 + quad * 4 + i > mloc) s[g][i] = -__builtin_inff();
    }
    // softmax: this lane owns ONE query row (16 of its 64 keys)
    float pf[4][4]; float rs = 0.0f;
    #pragma unroll
    for (int g = 0; g < 4; ++g)
      #pragma unroll
      for (int i = 0; i < 4; ++i) { pf[g][i] = __expf(s[g][i] - 12.0f); rs += pf[g][i]; }
    rs += __shfl_xor(rs, 16);
    rs += __shfl_xor(rs, 32);
    l_r[u] += rs;
    #pragma unroll
    for (int g = 0; g < 4; ++g) {
      uint2 pk2;
      pk2.x = cvtpk(pf[g][0], pf[g][1]);
      pk2.y = cvtpk(pf[g][2], pf[g][3]);
      *(uint2*)&ps[wq][n][(g * 16 + quad * 4) ^ ((n & 7) * 8)] = pk2;   // b64
    }
    // P back as B-frag (row n = query, k = key contiguous); same wave, no barrier
    const short8 pb0 = *(const short8*)&ps[wq][n][(quad * 8) ^ ((n & 7) * 8)];
    const short8 pb1 = *(const short8*)&ps[wq][n][(32 + quad * 8) ^ ((n & 7) * 8)];
    // O^T += V^T * P
    #pragma unroll
    for (int g = 0; g < 4; ++g) {
      const short8 vb0 = *(const short8*)&vs[g * 16 + n][(quad * 8) ^ ((n & 7) * 8)];
      acc[u][g] = __builtin_amdgcn_mfma_f32_16x16x32_bf16(vb0, pb0, acc[u][g], 0, 0, 0);
      const short8 vb1 = *(const short8*)&vs[g * 16 + n][(32 + quad * 8) ^ ((n & 7) * 8)];
      acc[u][g] = __builtin_amdgcn_mfma_f32_16x16x32_bf16(vb1, pb1, acc[u][g], 0, 0, 0);
    }
  };

  const int kmax = tiles[1];
  loadKV(0);
  for (int kt = 0; kt <= kmax; ++kt) {
    __syncthreads();
    *(short8*)&ks[sr][scs]      = kr0;
    *(short8*)&ks[sr + 32][scs] = kr1;
    *(short8*)&vs[sr][scs]      = vr0;
    *(short8*)&vs[sr + 32][scs] = vr1;
    __syncthreads();
    if (kt < kmax) loadKV(kt + 1);
    process(1, kt);                 // long tile, always active
    if (kt <= tiles[0]) process(0, kt);   // short tile: all but last iteration
  }

  // epilogue: y = O/l; remove projection onto normalized v (fp32 from vcmp)
  #pragma unroll
  for (int u = 0; u < 2; ++u) {
    const int tok = b * kT + tiles[u] * 64 + wq * 16 + n;
    const float invl = 1.0f / l_r[u];
    float4 vv[4]; float nn = 0.0f, syr = 0.0f;
    #pragma unroll
    for (int g = 0; g < 4; ++g) {
      vv[g] = *(const float4*)(vcmp + (size_t)tok * (kHKV * kD) + kv * kD + g * 16 + quad * 4);
      nn  += vv[g].x * vv[g].x + vv[g].y * vv[g].y + vv[g].z * vv[g].z + vv[g].w * vv[g].w;
      syr += acc[u][g][0] * vv[g].x + acc[u][g][1] * vv[g].y + acc[u][g][2] * vv[g].z + acc[u][g][3] * vv[g].w;
    }
    nn  += __shfl_xor(nn, 16);  nn  += __shfl_xor(nn, 32);
    syr += __shfl_xor(syr, 16); syr += __shfl_xor(syr, 32);
    const float inv = 1.0f / fmaxf(sqrtf(nn), 1e-12f);
    const float coef = syr * invl * inv * inv;
    #pragma unroll
    for (int g = 0; g < 4; ++g) {
      const float o0 = acc[u][g][0] * invl - coef * vv[g].x;
      const float o1 = acc[u][g][1] * invl - coef * vv[g].y;
      const float o2 = acc[u][g][2] * invl - coef * vv[g].z;
      const float o3 = acc[u][g][3] * invl - coef * vv[g].w;
      uint2 ow;
      ow.x = cvtpk(o0, o1);
      ow.y = cvtpk(o2, o3);
      *(uint2*)(yo + (size_t)tok * kDim + h * kD + g * 16 + quad * 4) = ow;
    }
  }
}

// ------------------------------- launch --------------------------------------
extern "C" void kernel_launch(void* const* d_in, const int* in_sizes, int n_in,
                              void* d_out, int out_size, void* d_ws, size_t ws_size,
                              hipStream_t stream) {
  (void)in_sizes; (void)n_in; (void)out_size; (void)ws_size;
  const float* x      = (const float*)d_in[0];
  const float* w_q    = (const float*)d_in[1];
  const float* w_k    = (const float*)d_in[2];
  const float* w_v    = (const float*)d_in[3];
  const float* w_proj = (const float*)d_in[4];
  const float* q_gain = (const float*)d_in[5];

  char* wsb = (char*)d_ws;
  u16* wqkv = (u16*)wsb;  wsb += (size_t)1536 * 1024 * 2;   // fused QKV weights
  u16* wpq  = (u16*)wsb;  wsb += (size_t)1024 * 1024 * 2;
  u16* xb   = (u16*)wsb;  wsb += (size_t)kTok * kDim * 2;
  u16* qh   = (u16*)wsb;  wsb += (size_t)kTok * kDim * 2;
  u16* khb  = (u16*)wsb;  wsb += (size_t)kTok * kHKV * kD * 2;
  u16* vTb  = (u16*)wsb;  wsb += (size_t)kTok * kHKV * kD * 2;
  u16* yo   = (u16*)wsb;  wsb += (size_t)kTok * kDim * 2;
  float* vcmp = (float*)wsb; wsb += (size_t)kTok * kHKV * kD * 4;
  float2* ropetab = (float2*)wsb; wsb += (size_t)kT * 16 * sizeof(float2);

  // 1) fused prep: rope table + x->bf16 + all weight fake-quant
  prep_kernel<<<4736, 256, 0, stream>>>(x, w_q, w_k, w_v, w_proj,
                                        xb, wqkv, wpq, ropetab);

  // 2) QKV GEMM with fused RMSNorm+RoPE+gain epilogue -> qh/kh/vT/vcmp
  gemm_qkv<<<dim3(24, 32), 256, 0, stream>>>(xb, wqkv, ropetab, q_gain,
                                             qh, khb, vTb, vcmp);

  // 3) adjacent-paired MFMA flash attention + projection removal -> yo (bf16)
  attn_mfma<<<dim3(16, kH, 2), 256, 0, stream>>>(qh, khb, vTb, vcmp, yo);

  // 4) output projection (fp32 out)
  gemm_out<<<dim3(16, 32), 256, 0, stream>>>(yo, wpq, (float*)d_out);
}

// Round 19
// 160.525 us; speedup vs baseline: 1.1490x; 1.1490x over previous
//
#include <hip/hip_runtime.h>
#include <math.h>

typedef unsigned short u16;
typedef __attribute__((ext_vector_type(8))) short short8;
typedef __attribute__((ext_vector_type(4))) float float4v;
typedef __attribute__((ext_vector_type(4))) u16 ushort4v;

namespace {
constexpr int kT    = 2048;
constexpr int kDim  = 1024;
constexpr int kH    = 16;
constexpr int kHKV  = 4;
constexpr int kD    = 64;
constexpr int kTok  = 4096;   // B*T
}

__device__ __forceinline__ u16 f2bf(float f) {
  unsigned int u = __builtin_bit_cast(unsigned int, f);
  u = (u + 0x7FFFu + ((u >> 16) & 1u)) >> 16;   // RNE
  return (u16)u;
}

// packed f32x2 -> bf16x2 (RNE, bitwise-identical to f2bf); lo = src0.
__device__ __forceinline__ unsigned int cvtpk(float lo, float hi) {
  unsigned int r;
  asm("v_cvt_pk_bf16_f32 %0, %1, %2" : "=v"(r) : "v"(lo), "v"(hi));
  return r;
}

// ---------------- fused prep: rope table + x->bf16 + 4x fake-quant -----------
// blocks [0,128): rope table; [128,2176): cvt x; [2176,4736): quant rows.
__global__ __launch_bounds__(256) void prep_kernel(
    const float* __restrict__ x,
    const float* __restrict__ w_q, const float* __restrict__ w_k,
    const float* __restrict__ w_v, const float* __restrict__ w_proj,
    u16* __restrict__ xb, u16* __restrict__ wqkv, u16* __restrict__ wpq,
    float2* __restrict__ ropetab)
{
  __shared__ float red[4];
  const int bid = blockIdx.x, tid = threadIdx.x;

  if (bid < 128) {                       // rope table (bitwise-same transcendentals)
    const int idx = bid * 256 + tid;     // 0..32767
    const int t = idx >> 4, i = idx & 15;
    const float fr = (float)t * powf(10000.0f, -(float)i * (1.0f / 16.0f));
    ropetab[idx] = make_float2(cosf(fr), sinf(fr));
    return;
  }
  if (bid < 2176) {                      // x -> bf16, 8 elems/thread
    const size_t i = ((size_t)(bid - 128) * 256 + tid) * 8;
    const float4 a = *(const float4*)(x + i);
    const float4 b = *(const float4*)(x + i + 4);
    uint4 o;
    o.x = cvtpk(a.x, a.y); o.y = cvtpk(a.z, a.w);
    o.z = cvtpk(b.x, b.y); o.w = cvtpk(b.z, b.w);
    *(uint4*)(xb + i) = o;
    return;
  }
  // fake-quant: one block per weight row (1024 cols, 4/thread, register-held)
  const int rid = bid - 2176;            // 0..2559
  const float* src; u16* dst; float halfv;
  if (rid < 1024)      { src = w_q    + (size_t)rid * 1024;          dst = wqkv + (size_t)rid * 1024;          halfv = 32.0f; }
  else if (rid < 1280) { src = w_k    + (size_t)(rid - 1024) * 1024; dst = wqkv + (size_t)rid * 1024;          halfv = 32.0f; }
  else if (rid < 1536) { src = w_v    + (size_t)(rid - 1280) * 1024; dst = wqkv + (size_t)rid * 1024;          halfv = 16.0f; }
  else                 { src = w_proj + (size_t)(rid - 1536) * 1024; dst = wpq  + (size_t)(rid - 1536) * 1024; halfv = 16.0f; }

  const float4 v4 = *(const float4*)(src + tid * 4);
  float mx = fmaxf(fmaxf(fabsf(v4.x), fabsf(v4.y)), fmaxf(fabsf(v4.z), fabsf(v4.w)));
  #pragma unroll
  for (int m = 1; m < 64; m <<= 1) mx = fmaxf(mx, __shfl_xor(mx, m));
  if ((tid & 63) == 0) red[tid >> 6] = mx;
  __syncthreads();
  mx = fmaxf(fmaxf(red[0], red[1]), fmaxf(red[2], red[3]));
  const float wmax = fmaxf(mx, 1e-5f);
  const float inv_half = 1.0f / halfv;
  const float vals[4] = {v4.x, v4.y, v4.z, v4.w};
  float q[4];
  #pragma unroll
  for (int j = 0; j < 4; ++j) {
    float r = rintf(vals[j] / wmax * halfv);
    r = fminf(fmaxf(r, -halfv), halfv - 1.0f);
    q[j] = r * inv_half * wmax;
  }
  uint2 o;
  o.x = cvtpk(q[0], q[1]); o.y = cvtpk(q[2], q[3]);
  *(uint2*)(dst + tid * 4) = o;
}

// ======== 128Mx64N bf16 MFMA GEMM core (4 waves x 32x64, BK=64) ==============
// Reg-staged global->LDS with XOR swizzle, BK=64: half the barriers of BK=32,
// 16 MFMA per barrier pair. Swizzle: physical col = logical col ^ ((row&7)*8),
// bijective within the 64-col row; reads use the same map (2-way max, free).
// Each wave: rows wm..wm+31 (mi in {0,1}), all 64 cols (ni 0..3).
// acc[mi][ni][i]: row = by*128 + wv*32 + mi*16 + quad*4 + i, col = ni*16 + n.
#define GEMM_CORE(A_, W_, K_, NCOL0_)                                          \
  __shared__ u16 As[128][64];                                                  \
  __shared__ u16 Bs[64][64];                                                   \
  const int tid = threadIdx.x;                                                 \
  const int lane = tid & 63, wv = tid >> 6;                                    \
  const int n = lane & 15, quad = lane >> 4;                                   \
  const int wm = wv * 32;                                                      \
  const int m0 = blockIdx.y * 128;                                             \
  const int sr = tid >> 3, sc = (tid & 7) * 8;                                 \
  const int scs = sc ^ ((sr & 7) * 8);                                         \
  float4v acc[2][4];                                                           \
  _Pragma("unroll")                                                            \
  for (int mi = 0; mi < 2; ++mi)                                               \
    _Pragma("unroll")                                                          \
    for (int ni = 0; ni < 4; ++ni) {                                           \
      acc[mi][ni][0]=0.f; acc[mi][ni][1]=0.f;                                  \
      acc[mi][ni][2]=0.f; acc[mi][ni][3]=0.f; }                                \
  short8 a0r, a1r, a2r, a3r, b0r, b1r;                                         \
  a0r = *(const short8*)(A_ + (size_t)(m0 + sr) * K_ + sc);                    \
  a1r = *(const short8*)(A_ + (size_t)(m0 + sr + 32) * K_ + sc);               \
  a2r = *(const short8*)(A_ + (size_t)(m0 + sr + 64) * K_ + sc);               \
  a3r = *(const short8*)(A_ + (size_t)(m0 + sr + 96) * K_ + sc);               \
  b0r = *(const short8*)(W_ + (size_t)(NCOL0_ + sr) * K_ + sc);                \
  b1r = *(const short8*)(W_ + (size_t)(NCOL0_ + sr + 32) * K_ + sc);           \
  for (int k0 = 0; k0 < K_; k0 += 64) {                                        \
    __syncthreads();                                                           \
    *(short8*)&As[sr][scs]      = a0r;  *(short8*)&As[sr + 32][scs] = a1r;     \
    *(short8*)&As[sr + 64][scs] = a2r;  *(short8*)&As[sr + 96][scs] = a3r;     \
    *(short8*)&Bs[sr][scs]      = b0r;  *(short8*)&Bs[sr + 32][scs] = b1r;     \
    __syncthreads();                                                           \
    if (k0 + 64 < K_) {                                                        \
      const int kn = k0 + 64 + sc;                                             \
      a0r = *(const short8*)(A_ + (size_t)(m0 + sr) * K_ + kn);                \
      a1r = *(const short8*)(A_ + (size_t)(m0 + sr + 32) * K_ + kn);           \
      a2r = *(const short8*)(A_ + (size_t)(m0 + sr + 64) * K_ + kn);           \
      a3r = *(const short8*)(A_ + (size_t)(m0 + sr + 96) * K_ + kn);           \
      b0r = *(const short8*)(W_ + (size_t)(NCOL0_ + sr) * K_ + kn);            \
      b1r = *(const short8*)(W_ + (size_t)(NCOL0_ + sr + 32) * K_ + kn);       \
    }                                                                          \
    _Pragma("unroll")                                                          \
    for (int kk = 0; kk < 64; kk += 32) {                                      \
      short8 af[2], bf[4];                                                     \
      _Pragma("unroll")                                                        \
      for (int mi = 0; mi < 2; ++mi)                                           \
        af[mi] = *(const short8*)&As[wm + mi * 16 + n][(kk + quad * 8) ^ ((n & 7) * 8)]; \
      _Pragma("unroll")                                                        \
      for (int ni = 0; ni < 4; ++ni)                                           \
        bf[ni] = *(const short8*)&Bs[ni * 16 + n][(kk + quad * 8) ^ ((n & 7) * 8)]; \
      _Pragma("unroll")                                                        \
      for (int mi = 0; mi < 2; ++mi)                                           \
        _Pragma("unroll")                                                      \
        for (int ni = 0; ni < 4; ++ni)                                         \
          acc[mi][ni] = __builtin_amdgcn_mfma_f32_16x16x32_bf16(af[mi], bf[ni], acc[mi][ni], 0, 0, 0); \
    }                                                                          \
  }

// -------- QKV GEMM with fused RMSNorm+RoPE+gain epilogue ---------------------
// Panel (blockIdx.x, 64 cols): 0..15 q head, 16..19 k head, 20..23 v head.
__global__ __launch_bounds__(256) void gemm_qkv(
    const u16* __restrict__ A, const u16* __restrict__ W,
    const float2* __restrict__ ropetab, const float* __restrict__ q_gain,
    u16* __restrict__ qh, u16* __restrict__ kh,
    u16* __restrict__ vT, float* __restrict__ vcmp)
{
  GEMM_CORE(A, W, kDim, (int)(blockIdx.x * 64))

  const int p = blockIdx.x;
  const int rbase = m0 + wm;                 // + mi*16 + quad*4 + i = token row
  const int bI = rbase >> 11;                // batch (128-row tiles never straddle)

  if (p < 20) {
    // q (head h=p) or k (head p-16): RMSNorm over 64 dims + RoPE + gain
    const float gain = (p < 16) ? q_gain[p] * 0.125f : 1.0f;
    u16* dst = (p < 16) ? qh + ((size_t)(bI * kH + p) * kT) * kD
                        : kh + ((size_t)(bI * kHKV + (p - 16)) * kT) * kD;
    #pragma unroll
    for (int mi = 0; mi < 2; ++mi)
      #pragma unroll
      for (int i = 0; i < 4; ++i) {
        const int row = rbase + mi * 16 + quad * 4 + i;
        const int t = row & (kT - 1);
        float v[4];
        #pragma unroll
        for (int ni = 0; ni < 4; ++ni) v[ni] = acc[mi][ni][i];
        float ss = v[0]*v[0] + v[1]*v[1] + v[2]*v[2] + v[3]*v[3];
        #pragma unroll
        for (int m = 1; m < 16; m <<= 1) ss += __shfl_xor(ss, m);
        const float rr = 1.0f / sqrtf(ss * (1.0f / 64.0f) + 1.1920929e-7f);
        #pragma unroll
        for (int ni = 0; ni < 4; ++ni) v[ni] *= rr;
        const float2 cs = ropetab[t * 16 + n];
        const float r0 =  v[0] * cs.x + v[1] * cs.y;
        const float r1 = -v[0] * cs.y + v[1] * cs.x;
        v[0] = r0; v[1] = r1;
        #pragma unroll
        for (int ni = 0; ni < 4; ++ni)
          dst[(size_t)t * kD + ni * 16 + n] = f2bf(v[ni] * gain);
      }
  } else {
    // v head kvh = p-20: bf16 V^T [b][kv][d][T] + compact fp32 v [tok][kv*64+d]
    const int kvh = p - 20;
    u16* vTb = vT + ((size_t)(bI * kHKV + kvh) * kD) * kT;
    #pragma unroll
    for (int mi = 0; mi < 2; ++mi) {
      const int t0 = (rbase + mi * 16 + quad * 4) & (kT - 1);
      #pragma unroll
      for (int ni = 0; ni < 4; ++ni) {
        const int d = ni * 16 + n;
        uint2 pk;
        pk.x = cvtpk(acc[mi][ni][0], acc[mi][ni][1]);
        pk.y = cvtpk(acc[mi][ni][2], acc[mi][ni][3]);
        *(uint2*)(vTb + (size_t)d * kT + t0) = pk;
        #pragma unroll
        for (int i = 0; i < 4; ++i)
          vcmp[(size_t)(rbase + mi * 16 + quad * 4 + i) * (kHKV * kD) + kvh * kD + d] = acc[mi][ni][i];
      }
    }
  }
}

// -------- output projection GEMM (fp32 C) ------------------------------------
__global__ __launch_bounds__(256) void gemm_out(
    const u16* __restrict__ A, const u16* __restrict__ W,
    float* __restrict__ C)
{
  GEMM_CORE(A, W, kDim, (int)(blockIdx.x * 64))
  const int n0 = blockIdx.x * 64;
  #pragma unroll
  for (int mi = 0; mi < 2; ++mi)
    #pragma unroll
    for (int ni = 0; ni < 4; ++ni)
      #pragma unroll
      for (int i = 0; i < 4; ++i)
        C[(size_t)(m0 + wm + mi * 16 + quad * 4 + i) * kDim + n0 + ni * 16 + n] = acc[mi][ni][i];
}

// ---------------- MFMA causal flash attention, S^T orientation ---------------
// R9 pairing {p, 31-p}: every block = exactly 33 process-units (balanced).
// S^T = mfma(K_frag, Q_frag): one softmax row per lane (quad-replicated).
// PV as O^T = mfma(V^T_frag, P_frag). Static max 12 (|q'|<=1.5, |k|=8).
__global__ __launch_bounds__(256) void attn_mfma(
    const u16* __restrict__ qh, const u16* __restrict__ kh,
    const u16* __restrict__ vT, const float* __restrict__ vcmp,
    u16* __restrict__ yo)
{
  __shared__ u16 ks[64][64];     // [key][d],   col ^= (key&7)*8
  __shared__ u16 vs[64][64];     // [d][key],   col ^= (d&7)*8   (V^T)
  __shared__ u16 ps[4][16][64];  // [wave][query][key], col ^= (query&7)*8

  const int tid = threadIdx.x;
  const int lane = tid & 63, wq = tid >> 6;
  const int n = lane & 15, quad = lane >> 4;
  const int p = blockIdx.x;                     // pair 0..15
  const int h = blockIdx.y, b = blockIdx.z;
  const int kv = h >> 2;
  const int tiles[2] = {p, 31 - p};             // tile 0 (short), tile 1 (long)
  const u16* kbase = kh + ((size_t)(b * kHKV + kv) * kT) * kD;
  const u16* vbase = vT + ((size_t)(b * kHKV + kv) * kD) * kT;

  short8 qa[2][2];                // Q B-frags (col=query n, k=d contiguous)
  {
    const u16* qb = qh + ((size_t)(b * kH + h) * kT) * kD;
    #pragma unroll
    for (int u = 0; u < 2; ++u) {
      const size_t row = (size_t)(tiles[u] * 64 + wq * 16 + n) * kD;
      qa[u][0] = *(const short8*)(qb + row + quad * 8);
      qa[u][1] = *(const short8*)(qb + row + 32 + quad * 8);
    }
  }

  const int sr = tid >> 3;            // 0..31 (+32 second chunk)
  const int sc = (tid & 7) * 8;
  const int scs = sc ^ ((sr & 7) * 8);

  float l_r[2] = {0.0f, 0.0f};
  float4v acc[2][4];                  // O^T: [u][d-block g][i]: d=g*16+quad*4+i, query=n
  #pragma unroll
  for (int u = 0; u < 2; ++u)
    #pragma unroll
    for (int g = 0; g < 4; ++g) { acc[u][g][0]=0.f; acc[u][g][1]=0.f; acc[u][g][2]=0.f; acc[u][g][3]=0.f; }

  short8 kr0, kr1, vr0, vr1;
  auto loadKV = [&](int kt) {
    kr0 = *(const short8*)(kbase + (size_t)(kt * 64 + sr) * kD + sc);
    kr1 = *(const short8*)(kbase + (size_t)(kt * 64 + sr + 32) * kD + sc);
    vr0 = *(const short8*)(vbase + (size_t)sr * kT + kt * 64 + sc);
    vr1 = *(const short8*)(vbase + (size_t)(sr + 32) * kT + kt * 64 + sc);
  };

  auto process = [&](int u, int kt) {
    float4v s[4];
    #pragma unroll
    for (int g = 0; g < 4; ++g) { s[g][0]=0.f; s[g][1]=0.f; s[g][2]=0.f; s[g][3]=0.f; }
    // S^T[key][query]: A = K rows, B = Q
    #pragma unroll
    for (int g = 0; g < 4; ++g) {
      const short8 kb0 = *(const short8*)&ks[g * 16 + n][(quad * 8) ^ ((n & 7) * 8)];
      s[g] = __builtin_amdgcn_mfma_f32_16x16x32_bf16(kb0, qa[u][0], s[g], 0, 0, 0);
      const short8 kb1 = *(const short8*)&ks[g * 16 + n][(32 + quad * 8) ^ ((n & 7) * 8)];
      s[g] = __builtin_amdgcn_mfma_f32_16x16x32_bf16(kb1, qa[u][1], s[g], 0, 0, 0);
    }
    if (kt == tiles[u]) {   // diagonal: mask key j > query m (local coords)
      const int mloc = wq * 16 + n;
      #pragma unroll
      for (int g = 0; g < 4; ++g)
        #pragma unroll
        for (int i = 0; i < 4; ++i)
          if (g * 16 + quad * 4 + i > mloc) s[g][i] = -__builtin_inff();
    }
    // softmax: this lane owns ONE query row (16 of its 64 keys)
    float pf[4][4]; float rs = 0.0f;
    #pragma unroll
    for (int g = 0; g < 4; ++g)
      #pragma unroll
      for (int i = 0; i < 4; ++i) { pf[g][i] = __expf(s[g][i] - 12.0f); rs += pf[g][i]; }
    rs += __shfl_xor(rs, 16);
    rs += __shfl_xor(rs, 32);
    l_r[u] += rs;
    #pragma unroll
    for (int g = 0; g < 4; ++g) {
      uint2 pk2;
      pk2.x = cvtpk(pf[g][0], pf[g][1]);
      pk2.y = cvtpk(pf[g][2], pf[g][3]);
      *(uint2*)&ps[wq][n][(g * 16 + quad * 4) ^ ((n & 7) * 8)] = pk2;   // b64
    }
    // P back as B-frag (row n = query, k = key contiguous); same wave, no barrier
    const short8 pb0 = *(const short8*)&ps[wq][n][(quad * 8) ^ ((n & 7) * 8)];
    const short8 pb1 = *(const short8*)&ps[wq][n][(32 + quad * 8) ^ ((n & 7) * 8)];
    // O^T += V^T * P
    #pragma unroll
    for (int g = 0; g < 4; ++g) {
      const short8 vb0 = *(const short8*)&vs[g * 16 + n][(quad * 8) ^ ((n & 7) * 8)];
      acc[u][g] = __builtin_amdgcn_mfma_f32_16x16x32_bf16(vb0, pb0, acc[u][g], 0, 0, 0);
      const short8 vb1 = *(const short8*)&vs[g * 16 + n][(32 + quad * 8) ^ ((n & 7) * 8)];
      acc[u][g] = __builtin_amdgcn_mfma_f32_16x16x32_bf16(vb1, pb1, acc[u][g], 0, 0, 0);
    }
  };

  const int kmax = tiles[1];
  loadKV(0);
  for (int kt = 0; kt <= kmax; ++kt) {
    __syncthreads();
    *(short8*)&ks[sr][scs]      = kr0;
    *(short8*)&ks[sr + 32][scs] = kr1;
    *(short8*)&vs[sr][scs]      = vr0;
    *(short8*)&vs[sr + 32][scs] = vr1;
    __syncthreads();
    if (kt < kmax) loadKV(kt + 1);
    process(1, kt);                 // long tile, always active
    if (kt <= tiles[0]) process(0, kt);
  }

  // epilogue: y = O/l; remove projection onto normalized v (fp32 from vcmp)
  #pragma unroll
  for (int u = 0; u < 2; ++u) {
    const int tok = b * kT + tiles[u] * 64 + wq * 16 + n;
    const float invl = 1.0f / l_r[u];
    float4 vv[4]; float nn = 0.0f, syr = 0.0f;
    #pragma unroll
    for (int g = 0; g < 4; ++g) {
      vv[g] = *(const float4*)(vcmp + (size_t)tok * (kHKV * kD) + kv * kD + g * 16 + quad * 4);
      nn  += vv[g].x * vv[g].x + vv[g].y * vv[g].y + vv[g].z * vv[g].z + vv[g].w * vv[g].w;
      syr += acc[u][g][0] * vv[g].x + acc[u][g][1] * vv[g].y + acc[u][g][2] * vv[g].z + acc[u][g][3] * vv[g].w;
    }
    nn  += __shfl_xor(nn, 16);  nn  += __shfl_xor(nn, 32);
    syr += __shfl_xor(syr, 16); syr += __shfl_xor(syr, 32);
    const float inv = 1.0f / fmaxf(sqrtf(nn), 1e-12f);
    const float coef = syr * invl * inv * inv;
    #pragma unroll
    for (int g = 0; g < 4; ++g) {
      const float o0 = acc[u][g][0] * invl - coef * vv[g].x;
      const float o1 = acc[u][g][1] * invl - coef * vv[g].y;
      const float o2 = acc[u][g][2] * invl - coef * vv[g].z;
      const float o3 = acc[u][g][3] * invl - coef * vv[g].w;
      uint2 ow;
      ow.x = cvtpk(o0, o1);
      ow.y = cvtpk(o2, o3);
      *(uint2*)(yo + (size_t)tok * kDim + h * kD + g * 16 + quad * 4) = ow;
    }
  }
}

// ------------------------------- launch --------------------------------------
extern "C" void kernel_launch(void* const* d_in, const int* in_sizes, int n_in,
                              void* d_out, int out_size, void* d_ws, size_t ws_size,
                              hipStream_t stream) {
  (void)in_sizes; (void)n_in; (void)out_size; (void)ws_size;
  const float* x      = (const float*)d_in[0];
  const float* w_q    = (const float*)d_in[1];
  const float* w_k    = (const float*)d_in[2];
  const float* w_v    = (const float*)d_in[3];
  const float* w_proj = (const float*)d_in[4];
  const float* q_gain = (const float*)d_in[5];

  char* wsb = (char*)d_ws;
  u16* wqkv = (u16*)wsb;  wsb += (size_t)1536 * 1024 * 2;   // fused QKV weights
  u16* wpq  = (u16*)wsb;  wsb += (size_t)1024 * 1024 * 2;
  u16* xb   = (u16*)wsb;  wsb += (size_t)kTok * kDim * 2;
  u16* qh   = (u16*)wsb;  wsb += (size_t)kTok * kDim * 2;
  u16* khb  = (u16*)wsb;  wsb += (size_t)kTok * kHKV * kD * 2;
  u16* vTb  = (u16*)wsb;  wsb += (size_t)kTok * kHKV * kD * 2;
  u16* yo   = (u16*)wsb;  wsb += (size_t)kTok * kDim * 2;
  float* vcmp = (float*)wsb; wsb += (size_t)kTok * kHKV * kD * 4;
  float2* ropetab = (float2*)wsb; wsb += (size_t)kT * 16 * sizeof(float2);

  // 1) fused prep: rope table + x->bf16 + all weight fake-quant
  prep_kernel<<<4736, 256, 0, stream>>>(x, w_q, w_k, w_v, w_proj,
                                        xb, wqkv, wpq, ropetab);

  // 2) QKV GEMM with fused RMSNorm+RoPE+gain epilogue -> qh/kh/vT/vcmp
  gemm_qkv<<<dim3(24, 32), 256, 0, stream>>>(xb, wqkv, ropetab, q_gain,
                                             qh, khb, vTb, vcmp);

  // 3) paired MFMA flash attention + projection removal -> yo (bf16)
  attn_mfma<<<dim3(16, kH, 2), 256, 0, stream>>>(qh, khb, vTb, vcmp, yo);

  // 4) output projection (fp32 out)
  gemm_out<<<dim3(16, 32), 256, 0, stream>>>(yo, wpq, (float*)d_out);
}

// Round 22
// 160.489 us; speedup vs baseline: 1.1493x; 1.0002x over previous
//
#include <hip/hip_runtime.h>
#include <math.h>

typedef unsigned short u16;
typedef __attribute__((ext_vector_type(8))) short short8;
typedef __attribute__((ext_vector_type(4))) float float4v;
typedef __attribute__((ext_vector_type(4))) u16 ushort4v;

namespace {
constexpr int kT    = 2048;
constexpr int kDim  = 1024;
constexpr int kH    = 16;
constexpr int kHKV  = 4;
constexpr int kD    = 64;
constexpr int kTok  = 4096;   // B*T
}

__device__ __forceinline__ u16 f2bf(float f) {
  unsigned int u = __builtin_bit_cast(unsigned int, f);
  u = (u + 0x7FFFu + ((u >> 16) & 1u)) >> 16;   // RNE
  return (u16)u;
}

// packed f32x2 -> bf16x2 (RNE, bitwise-identical to f2bf); lo = src0.
__device__ __forceinline__ unsigned int cvtpk(float lo, float hi) {
  unsigned int r;
  asm("v_cvt_pk_bf16_f32 %0, %1, %2" : "=v"(r) : "v"(lo), "v"(hi));
  return r;
}

// ---------------- fused prep: rope table + x->bf16 + 4x fake-quant -----------
// blocks [0,128): rope table; [128,2176): cvt x; [2176,4736): quant rows.
__global__ __launch_bounds__(256) void prep_kernel(
    const float* __restrict__ x,
    const float* __restrict__ w_q, const float* __restrict__ w_k,
    const float* __restrict__ w_v, const float* __restrict__ w_proj,
    u16* __restrict__ xb, u16* __restrict__ wqkv, u16* __restrict__ wpq,
    float2* __restrict__ ropetab)
{
  __shared__ float red[4];
  const int bid = blockIdx.x, tid = threadIdx.x;

  if (bid < 128) {                       // rope table (bitwise-same transcendentals)
    const int idx = bid * 256 + tid;     // 0..32767
    const int t = idx >> 4, i = idx & 15;
    const float fr = (float)t * powf(10000.0f, -(float)i * (1.0f / 16.0f));
    ropetab[idx] = make_float2(cosf(fr), sinf(fr));
    return;
  }
  if (bid < 2176) {                      // x -> bf16, 8 elems/thread
    const size_t i = ((size_t)(bid - 128) * 256 + tid) * 8;
    const float4 a = *(const float4*)(x + i);
    const float4 b = *(const float4*)(x + i + 4);
    uint4 o;
    o.x = cvtpk(a.x, a.y); o.y = cvtpk(a.z, a.w);
    o.z = cvtpk(b.x, b.y); o.w = cvtpk(b.z, b.w);
    *(uint4*)(xb + i) = o;
    return;
  }
  // fake-quant: one block per weight row (1024 cols, 4/thread, register-held)
  const int rid = bid - 2176;            // 0..2559
  const float* src; u16* dst; float halfv;
  if (rid < 1024)      { src = w_q    + (size_t)rid * 1024;          dst = wqkv + (size_t)rid * 1024;          halfv = 32.0f; }
  else if (rid < 1280) { src = w_k    + (size_t)(rid - 1024) * 1024; dst = wqkv + (size_t)rid * 1024;          halfv = 32.0f; }
  else if (rid < 1536) { src = w_v    + (size_t)(rid - 1280) * 1024; dst = wqkv + (size_t)rid * 1024;          halfv = 16.0f; }
  else                 { src = w_proj + (size_t)(rid - 1536) * 1024; dst = wpq  + (size_t)(rid - 1536) * 1024; halfv = 16.0f; }

  const float4 v4 = *(const float4*)(src + tid * 4);
  float mx = fmaxf(fmaxf(fabsf(v4.x), fabsf(v4.y)), fmaxf(fabsf(v4.z), fabsf(v4.w)));
  #pragma unroll
  for (int m = 1; m < 64; m <<= 1) mx = fmaxf(mx, __shfl_xor(mx, m));
  if ((tid & 63) == 0) red[tid >> 6] = mx;
  __syncthreads();
  mx = fmaxf(fmaxf(red[0], red[1]), fmaxf(red[2], red[3]));
  const float wmax = fmaxf(mx, 1e-5f);
  const float inv_half = 1.0f / halfv;
  const float vals[4] = {v4.x, v4.y, v4.z, v4.w};
  float q[4];
  #pragma unroll
  for (int j = 0; j < 4; ++j) {
    float r = rintf(vals[j] / wmax * halfv);
    r = fminf(fmaxf(r, -halfv), halfv - 1.0f);
    q[j] = r * inv_half * wmax;
  }
  uint2 o;
  o.x = cvtpk(q[0], q[1]); o.y = cvtpk(q[2], q[3]);
  *(uint2*)(dst + tid * 4) = o;
}

// ======== 128Mx64N bf16 MFMA GEMM core (4 waves x 32x64, BK=64) ==============
// Reg-staged global->LDS with XOR swizzle, BK=64 (R19 measured-best).
// Swizzle: physical col = logical col ^ ((row&7)*8); same map on reads.
// acc[mi][ni][i]: row = by*128 + wv*32 + mi*16 + quad*4 + i, col = ni*16 + n.
#define GEMM_CORE(A_, W_, K_, NCOL0_)                                          \
  __shared__ u16 As[128][64];                                                  \
  __shared__ u16 Bs[64][64];                                                   \
  const int tid = threadIdx.x;                                                 \
  const int lane = tid & 63, wv = tid >> 6;                                    \
  const int n = lane & 15, quad = lane >> 4;                                   \
  const int wm = wv * 32;                                                      \
  const int m0 = blockIdx.y * 128;                                             \
  const int sr = tid >> 3, sc = (tid & 7) * 8;                                 \
  const int scs = sc ^ ((sr & 7) * 8);                                         \
  float4v acc[2][4];                                                           \
  _Pragma("unroll")                                                            \
  for (int mi = 0; mi < 2; ++mi)                                               \
    _Pragma("unroll")                                                          \
    for (int ni = 0; ni < 4; ++ni) {                                           \
      acc[mi][ni][0]=0.f; acc[mi][ni][1]=0.f;                                  \
      acc[mi][ni][2]=0.f; acc[mi][ni][3]=0.f; }                                \
  short8 a0r, a1r, a2r, a3r, b0r, b1r;                                         \
  a0r = *(const short8*)(A_ + (size_t)(m0 + sr) * K_ + sc);                    \
  a1r = *(const short8*)(A_ + (size_t)(m0 + sr + 32) * K_ + sc);               \
  a2r = *(const short8*)(A_ + (size_t)(m0 + sr + 64) * K_ + sc);               \
  a3r = *(const short8*)(A_ + (size_t)(m0 + sr + 96) * K_ + sc);               \
  b0r = *(const short8*)(W_ + (size_t)(NCOL0_ + sr) * K_ + sc);                \
  b1r = *(const short8*)(W_ + (size_t)(NCOL0_ + sr + 32) * K_ + sc);           \
  for (int k0 = 0; k0 < K_; k0 += 64) {                                        \
    __syncthreads();                                                           \
    *(short8*)&As[sr][scs]      = a0r;  *(short8*)&As[sr + 32][scs] = a1r;     \
    *(short8*)&As[sr + 64][scs] = a2r;  *(short8*)&As[sr + 96][scs] = a3r;     \
    *(short8*)&Bs[sr][scs]      = b0r;  *(short8*)&Bs[sr + 32][scs] = b1r;     \
    __syncthreads();                                                           \
    if (k0 + 64 < K_) {                                                        \
      const int kn = k0 + 64 + sc;                                             \
      a0r = *(const short8*)(A_ + (size_t)(m0 + sr) * K_ + kn);                \
      a1r = *(const short8*)(A_ + (size_t)(m0 + sr + 32) * K_ + kn);           \
      a2r = *(const short8*)(A_ + (size_t)(m0 + sr + 64) * K_ + kn);           \
      a3r = *(const short8*)(A_ + (size_t)(m0 + sr + 96) * K_ + kn);           \
      b0r = *(const short8*)(W_ + (size_t)(NCOL0_ + sr) * K_ + kn);            \
      b1r = *(const short8*)(W_ + (size_t)(NCOL0_ + sr + 32) * K_ + kn);       \
    }                                                                          \
    _Pragma("unroll")                                                          \
    for (int kk = 0; kk < 64; kk += 32) {                                      \
      short8 af[2], bf[4];                                                     \
      _Pragma("unroll")                                                        \
      for (int mi = 0; mi < 2; ++mi)                                           \
        af[mi] = *(const short8*)&As[wm + mi * 16 + n][(kk + quad * 8) ^ ((n & 7) * 8)]; \
      _Pragma("unroll")                                                        \
      for (int ni = 0; ni < 4; ++ni)                                           \
        bf[ni] = *(const short8*)&Bs[ni * 16 + n][(kk + quad * 8) ^ ((n & 7) * 8)]; \
      _Pragma("unroll")                                                        \
      for (int mi = 0; mi < 2; ++mi)                                           \
        _Pragma("unroll")                                                      \
        for (int ni = 0; ni < 4; ++ni)                                         \
          acc[mi][ni] = __builtin_amdgcn_mfma_f32_16x16x32_bf16(af[mi], bf[ni], acc[mi][ni], 0, 0, 0); \
    }                                                                          \
  }

// -------- QKV GEMM with fused RMSNorm+RoPE+gain epilogue ---------------------
// Panel (blockIdx.x, 64 cols): 0..15 q head, 16..19 k head, 20..23 v head.
__global__ __launch_bounds__(256) void gemm_qkv(
    const u16* __restrict__ A, const u16* __restrict__ W,
    const float2* __restrict__ ropetab, const float* __restrict__ q_gain,
    u16* __restrict__ qh, u16* __restrict__ kh,
    u16* __restrict__ vT, float* __restrict__ vcmp)
{
  GEMM_CORE(A, W, kDim, (int)(blockIdx.x * 64))

  const int p = blockIdx.x;
  const int rbase = m0 + wm;                 // + mi*16 + quad*4 + i = token row
  const int bI = rbase >> 11;                // batch (128-row tiles never straddle)

  if (p < 20) {
    // q (head h=p) or k (head p-16): RMSNorm over 64 dims + RoPE + gain
    const float gain = (p < 16) ? q_gain[p] * 0.125f : 1.0f;
    u16* dst = (p < 16) ? qh + ((size_t)(bI * kH + p) * kT) * kD
                        : kh + ((size_t)(bI * kHKV + (p - 16)) * kT) * kD;
    #pragma unroll
    for (int mi = 0; mi < 2; ++mi)
      #pragma unroll
      for (int i = 0; i < 4; ++i) {
        const int row = rbase + mi * 16 + quad * 4 + i;
        const int t = row & (kT - 1);
        float v[4];
        #pragma unroll
        for (int ni = 0; ni < 4; ++ni) v[ni] = acc[mi][ni][i];
        float ss = v[0]*v[0] + v[1]*v[1] + v[2]*v[2] + v[3]*v[3];
        #pragma unroll
        for (int m = 1; m < 16; m <<= 1) ss += __shfl_xor(ss, m);
        const float rr = 1.0f / sqrtf(ss * (1.0f / 64.0f) + 1.1920929e-7f);
        #pragma unroll
        for (int ni = 0; ni < 4; ++ni) v[ni] *= rr;
        const float2 cs = ropetab[t * 16 + n];
        const float r0 =  v[0] * cs.x + v[1] * cs.y;
        const float r1 = -v[0] * cs.y + v[1] * cs.x;
        v[0] = r0; v[1] = r1;
        #pragma unroll
        for (int ni = 0; ni < 4; ++ni)
          dst[(size_t)t * kD + ni * 16 + n] = f2bf(v[ni] * gain);
      }
  } else {
    // v head kvh = p-20: bf16 V^T [b][kv][d][T] + compact fp32 v [tok][kv*64+d]
    const int kvh = p - 20;
    u16* vTb = vT + ((size_t)(bI * kHKV + kvh) * kD) * kT;
    #pragma unroll
    for (int mi = 0; mi < 2; ++mi) {
      const int t0 = (rbase + mi * 16 + quad * 4) & (kT - 1);
      #pragma unroll
      for (int ni = 0; ni < 4; ++ni) {
        const int d = ni * 16 + n;
        uint2 pk;
        pk.x = cvtpk(acc[mi][ni][0], acc[mi][ni][1]);
        pk.y = cvtpk(acc[mi][ni][2], acc[mi][ni][3]);
        *(uint2*)(vTb + (size_t)d * kT + t0) = pk;
        #pragma unroll
        for (int i = 0; i < 4; ++i)
          vcmp[(size_t)(rbase + mi * 16 + quad * 4 + i) * (kHKV * kD) + kvh * kD + d] = acc[mi][ni][i];
      }
    }
  }
}

// -------- output projection GEMM (fp32 C) ------------------------------------
__global__ __launch_bounds__(256) void gemm_out(
    const u16* __restrict__ A, const u16* __restrict__ W,
    float* __restrict__ C)
{
  GEMM_CORE(A, W, kDim, (int)(blockIdx.x * 64))
  const int n0 = blockIdx.x * 64;
  #pragma unroll
  for (int mi = 0; mi < 2; ++mi)
    #pragma unroll
    for (int ni = 0; ni < 4; ++ni)
      #pragma unroll
      for (int i = 0; i < 4; ++i)
        C[(size_t)(m0 + wm + mi * 16 + quad * 4 + i) * kDim + n0 + ni * 16 + n] = acc[mi][ni][i];
}

// ---------------- MFMA causal flash attention, S^T orientation ---------------
// R9 pairing {p, 31-p}: every block = exactly 33 process-units (balanced).
// DOUBLE-BUFFERED ks/vs: ONE barrier per K-tile iteration (was two).
// Safety: a wave writing buf[b^1] at iter kt+1 conflicts only with reads of
// buf[b^1] at iter kt-1; those completed before the iter-kt barrier that the
// writer already passed (program order: write, barrier, compute).
// S^T = mfma(K_frag, Q_frag): one softmax row per lane (quad-replicated).
// PV as O^T = mfma(V^T_frag, P_frag). Static max 12 (|q'|<=1.5, |k|=8).
__global__ __launch_bounds__(256) void attn_mfma(
    const u16* __restrict__ qh, const u16* __restrict__ kh,
    const u16* __restrict__ vT, const float* __restrict__ vcmp,
    u16* __restrict__ yo)
{
  __shared__ u16 ks[2][64][64];  // [buf][key][d], col ^= (key&7)*8
  __shared__ u16 vs[2][64][64];  // [buf][d][key], col ^= (d&7)*8   (V^T)
  __shared__ u16 ps[4][16][64];  // [wave][query][key], col ^= (query&7)*8

  const int tid = threadIdx.x;
  const int lane = tid & 63, wq = tid >> 6;
  const int n = lane & 15, quad = lane >> 4;
  const int p = blockIdx.x;                     // pair 0..15
  const int h = blockIdx.y, b = blockIdx.z;
  const int kv = h >> 2;
  const int tiles[2] = {p, 31 - p};             // tile 0 (short), tile 1 (long)
  const u16* kbase = kh + ((size_t)(b * kHKV + kv) * kT) * kD;
  const u16* vbase = vT + ((size_t)(b * kHKV + kv) * kD) * kT;

  short8 qa[2][2];                // Q B-frags (col=query n, k=d contiguous)
  {
    const u16* qb = qh + ((size_t)(b * kH + h) * kT) * kD;
    #pragma unroll
    for (int u = 0; u < 2; ++u) {
      const size_t row = (size_t)(tiles[u] * 64 + wq * 16 + n) * kD;
      qa[u][0] = *(const short8*)(qb + row + quad * 8);
      qa[u][1] = *(const short8*)(qb + row + 32 + quad * 8);
    }
  }

  const int sr = tid >> 3;            // 0..31 (+32 second chunk)
  const int sc = (tid & 7) * 8;
  const int scs = sc ^ ((sr & 7) * 8);

  float l_r[2] = {0.0f, 0.0f};
  float4v acc[2][4];                  // O^T: [u][d-block g][i]: d=g*16+quad*4+i, query=n
  #pragma unroll
  for (int u = 0; u < 2; ++u)
    #pragma unroll
    for (int g = 0; g < 4; ++g) { acc[u][g][0]=0.f; acc[u][g][1]=0.f; acc[u][g][2]=0.f; acc[u][g][3]=0.f; }

  short8 kr0, kr1, vr0, vr1;
  auto loadKV = [&](int kt) {
    kr0 = *(const short8*)(kbase + (size_t)(kt * 64 + sr) * kD + sc);
    kr1 = *(const short8*)(kbase + (size_t)(kt * 64 + sr + 32) * kD + sc);
    vr0 = *(const short8*)(vbase + (size_t)sr * kT + kt * 64 + sc);
    vr1 = *(const short8*)(vbase + (size_t)(sr + 32) * kT + kt * 64 + sc);
  };

  auto process = [&](int u, int kt, int bb) {
    float4v s[4];
    #pragma unroll
    for (int g = 0; g < 4; ++g) { s[g][0]=0.f; s[g][1]=0.f; s[g][2]=0.f; s[g][3]=0.f; }
    // S^T[key][query]: A = K rows, B = Q
    #pragma unroll
    for (int g = 0; g < 4; ++g) {
      const short8 kb0 = *(const short8*)&ks[bb][g * 16 + n][(quad * 8) ^ ((n & 7) * 8)];
      s[g] = __builtin_amdgcn_mfma_f32_16x16x32_bf16(kb0, qa[u][0], s[g], 0, 0, 0);
      const short8 kb1 = *(const short8*)&ks[bb][g * 16 + n][(32 + quad * 8) ^ ((n & 7) * 8)];
      s[g] = __builtin_amdgcn_mfma_f32_16x16x32_bf16(kb1, qa[u][1], s[g], 0, 0, 0);
    }
    if (kt == tiles[u]) {   // diagonal: mask key j > query m (local coords)
      const int mloc = wq * 16 + n;
      #pragma unroll
      for (int g = 0; g < 4; ++g)
        #pragma unroll
        for (int i = 0; i < 4; ++i)
          if (g * 16 + quad * 4 + i > mloc) s[g][i] = -__builtin_inff();
    }
    // softmax: this lane owns ONE query row (16 of its 64 keys)
    float pf[4][4]; float rs = 0.0f;
    #pragma unroll
    for (int g = 0; g < 4; ++g)
      #pragma unroll
      for (int i = 0; i < 4; ++i) { pf[g][i] = __expf(s[g][i] - 12.0f); rs += pf[g][i]; }
    rs += __shfl_xor(rs, 16);
    rs += __shfl_xor(rs, 32);
    l_r[u] += rs;
    #pragma unroll
    for (int g = 0; g < 4; ++g) {
      uint2 pk2;
      pk2.x = cvtpk(pf[g][0], pf[g][1]);
      pk2.y = cvtpk(pf[g][2], pf[g][3]);
      *(uint2*)&ps[wq][n][(g * 16 + quad * 4) ^ ((n & 7) * 8)] = pk2;   // b64
    }
    // P back as B-frag (row n = query, k = key contiguous); same wave, no barrier
    const short8 pb0 = *(const short8*)&ps[wq][n][(quad * 8) ^ ((n & 7) * 8)];
    const short8 pb1 = *(const short8*)&ps[wq][n][(32 + quad * 8) ^ ((n & 7) * 8)];
    // O^T += V^T * P
    #pragma unroll
    for (int g = 0; g < 4; ++g) {
      const short8 vb0 = *(const short8*)&vs[bb][g * 16 + n][(quad * 8) ^ ((n & 7) * 8)];
      acc[u][g] = __builtin_amdgcn_mfma_f32_16x16x32_bf16(vb0, pb0, acc[u][g], 0, 0, 0);
      const short8 vb1 = *(const short8*)&vs[bb][g * 16 + n][(32 + quad * 8) ^ ((n & 7) * 8)];
      acc[u][g] = __builtin_amdgcn_mfma_f32_16x16x32_bf16(vb1, pb1, acc[u][g], 0, 0, 0);
    }
  };

  const int kmax = tiles[1];
  loadKV(0);
  for (int kt = 0; kt <= kmax; ++kt) {
    const int bb = kt & 1;
    *(short8*)&ks[bb][sr][scs]      = kr0;
    *(short8*)&ks[bb][sr + 32][scs] = kr1;
    *(short8*)&vs[bb][sr][scs]      = vr0;
    *(short8*)&vs[bb][sr + 32][scs] = vr1;
    __syncthreads();
    if (kt < kmax) loadKV(kt + 1);
    process(1, kt, bb);             // long tile, always active
    if (kt <= tiles[0]) process(0, kt, bb);
  }

  // epilogue: y = O/l; remove projection onto normalized v (fp32 from vcmp)
  #pragma unroll
  for (int u = 0; u < 2; ++u) {
    const int tok = b * kT + tiles[u] * 64 + wq * 16 + n;
    const float invl = 1.0f / l_r[u];
    float4 vv[4]; float nn = 0.0f, syr = 0.0f;
    #pragma unroll
    for (int g = 0; g < 4; ++g) {
      vv[g] = *(const float4*)(vcmp + (size_t)tok * (kHKV * kD) + kv * kD + g * 16 + quad * 4);
      nn  += vv[g].x * vv[g].x + vv[g].y * vv[g].y + vv[g].z * vv[g].z + vv[g].w * vv[g].w;
      syr += acc[u][g][0] * vv[g].x + acc[u][g][1] * vv[g].y + acc[u][g][2] * vv[g].z + acc[u][g][3] * vv[g].w;
    }
    nn  += __shfl_xor(nn, 16);  nn  += __shfl_xor(nn, 32);
    syr += __shfl_xor(syr, 16); syr += __shfl_xor(syr, 32);
    const float inv = 1.0f / fmaxf(sqrtf(nn), 1e-12f);
    const float coef = syr * invl * inv * inv;
    #pragma unroll
    for (int g = 0; g < 4; ++g) {
      const float o0 = acc[u][g][0] * invl - coef * vv[g].x;
      const float o1 = acc[u][g][1] * invl - coef * vv[g].y;
      const float o2 = acc[u][g][2] * invl - coef * vv[g].z;
      const float o3 = acc[u][g][3] * invl - coef * vv[g].w;
      uint2 ow;
      ow.x = cvtpk(o0, o1);
      ow.y = cvtpk(o2, o3);
      *(uint2*)(yo + (size_t)tok * kDim + h * kD + g * 16 + quad * 4) = ow;
    }
  }
}

// ------------------------------- launch --------------------------------------
extern "C" void kernel_launch(void* const* d_in, const int* in_sizes, int n_in,
                              void* d_out, int out_size, void* d_ws, size_t ws_size,
                              hipStream_t stream) {
  (void)in_sizes; (void)n_in; (void)out_size; (void)ws_size;
  const float* x      = (const float*)d_in[0];
  const float* w_q    = (const float*)d_in[1];
  const float* w_k    = (const float*)d_in[2];
  const float* w_v    = (const float*)d_in[3];
  const float* w_proj = (const float*)d_in[4];
  const float* q_gain = (const float*)d_in[5];

  char* wsb = (char*)d_ws;
  u16* wqkv = (u16*)wsb;  wsb += (size_t)1536 * 1024 * 2;   // fused QKV weights
  u16* wpq  = (u16*)wsb;  wsb += (size_t)1024 * 1024 * 2;
  u16* xb   = (u16*)wsb;  wsb += (size_t)kTok * kDim * 2;
  u16* qh   = (u16*)wsb;  wsb += (size_t)kTok * kDim * 2;
  u16* khb  = (u16*)wsb;  wsb += (size_t)kTok * kHKV * kD * 2;
  u16* vTb  = (u16*)wsb;  wsb += (size_t)kTok * kHKV * kD * 2;
  u16* yo   = (u16*)wsb;  wsb += (size_t)kTok * kDim * 2;
  float* vcmp = (float*)wsb; wsb += (size_t)kTok * kHKV * kD * 4;
  float2* ropetab = (float2*)wsb; wsb += (size_t)kT * 16 * sizeof(float2);

  // 1) fused prep: rope table + x->bf16 + all weight fake-quant
  prep_kernel<<<4736, 256, 0, stream>>>(x, w_q, w_k, w_v, w_proj,
                                        xb, wqkv, wpq, ropetab);

  // 2) QKV GEMM with fused RMSNorm+RoPE+gain epilogue -> qh/kh/vT/vcmp
  gemm_qkv<<<dim3(24, 32), 256, 0, stream>>>(xb, wqkv, ropetab, q_gain,
                                             qh, khb, vTb, vcmp);

  // 3) paired MFMA flash attention + projection removal -> yo (bf16)
  attn_mfma<<<dim3(16, kH, 2), 256, 0, stream>>>(qh, khb, vTb, vcmp, yo);

  // 4) output projection (fp32 out)
  gemm_out<<<dim3(16, 32), 256, 0, stream>>>(yo, wpq, (float*)d_out);
}